// Round 9
// baseline (242.265 us; speedup 1.0000x reference)
//
#include <hip/hip_runtime.h>

#define B_ 32
#define T_ 2048
#define N_ 128
#define K_ 5
#define BN_ (B_ * N_)
#define PMAX_ 512
#define MINP_ 2

static constexpr double PI_D = 3.14159265358979323846264338327950288;
static constexpr float  S2_F = 0.70710678118654752440f;  // sqrt(1/2)

typedef float vf4 __attribute__((ext_vector_type(4)));

struct cf { float r, i; };

__device__ __forceinline__ void bf_w(cf& u, cf& v, float wr, float wi) {
    const float tr = v.r * wr - v.i * wi;
    const float ti = v.r * wi + v.i * wr;
    v.r = u.r - tr; v.i = u.i - ti;
    u.r += tr;      u.i += ti;
}
__device__ __forceinline__ void bf_1(cf& u, cf& v) {        // w = 1
    const float tr = v.r, ti = v.i;
    v.r = u.r - tr; v.i = u.i - ti;
    u.r += tr;      u.i += ti;
}
__device__ __forceinline__ void bf_mi(cf& u, cf& v) {       // w = -i
    const float tr = v.i, ti = -v.r;
    v.r = u.r - tr; v.i = u.i - ti;
    u.r += tr;      u.i += ti;
}
// LDS bank swizzle: keeps every hot access pattern low-way on 32 banks.
__device__ __forceinline__ int sw(int i) { return i ^ ((i >> 5) & 31); }

// lgkm-only barrier: orders ALL LDS traffic across the block WITHOUT
// draining vmcnt — global stores stay in flight across it (HIP's
// __syncthreads drains vmcnt(0), serializing stores against compute).
// memory-clobber asm on both sides pins ds ops; sched_barrier pins scheduling.
__device__ __forceinline__ void bar_lgkm() {
    __builtin_amdgcn_sched_barrier(0);
    asm volatile("s_waitcnt lgkmcnt(0)" ::: "memory");
    __builtin_amdgcn_s_barrier();
    asm volatile("" ::: "memory");
    __builtin_amdgcn_sched_barrier(0);
}

// ---------------------------------------------------------------------------
// Kernel 0: twiddle table tw[m] = exp(-2*pi*i*m/2048) as float2, into d_ws.
// ---------------------------------------------------------------------------
__global__ __launch_bounds__(256) void pt_twiddle(float2* __restrict__ tw) {
    const int m = blockIdx.x * 256 + threadIdx.x;
    if (m < 1024) {
        double s, c;
        sincos(-2.0 * PI_D * (double)m / 2048.0, &s, &c);
        tw[m] = make_float2((float)c, (float)s);
    }
}

// ---------------------------------------------------------------------------
// v9: R4 data path, software-pipelined over TWO series-pairs per block.
//  - 1024 blocks x 4 columns each; both pairs loaded up front as float4
//    (16B/512B line coalescing, half the load instructions of R4).
//  - All barriers are lgkm-only -> pair-P tile stores drain during pair-
//    (P+1)'s load/FFT/top-5 instead of serializing at the next barrier.
//  - Separate FFT (re/im) and seq (sqA/sqB) LDS buffers so restore/store
//    of pair P never collides with FFT of pair P+1. 33 KB -> 4 blocks/CU,
//    grid = exactly one resident generation.
// ---------------------------------------------------------------------------
__global__ __launch_bounds__(256, 4) void pt_fft_tiles(const float* __restrict__ x,
                                                       float* __restrict__ out,
                                                       const float2* __restrict__ tw) {
    __shared__ __align__(16) float re[2052];
    __shared__ __align__(16) float im[2052];
    __shared__ __align__(16) float sqA[2052];   // +4 slack for shifted f4 reads
    __shared__ __align__(16) float sqB[2052];
    __shared__ int sh_take[2][K_];

    // XCD-aware swizzle, bijective on [0,1024): blocks sharing (i0&7)
    // (likely same XCD) get consecutive q -> adjacent x columns.
    const int i0  = blockIdx.x;
    const int q   = ((i0 & 7) << 7) | (i0 >> 3);
    const int bnb = q * 4;             // 4 columns per block
    const int b   = bnb >> 7;          // / N_   (same b for all 4 cols)
    const int n   = bnb & 127;         // multiple of 4
    const int tid = threadIdx.x;

    // ---- Load all 4 columns up front: one float4 per (thread, m).
    // sv[m] = (A0,B0,A1,B1) for pairs P=0 (x,y) and P=1 (z,w).
    const float* xp = x + (size_t)b * T_ * N_ + n;
    vf4 sv[8];
#pragma unroll
    for (int m = 0; m < 8; ++m)
        sv[m] = *(const vf4*)(xp + (size_t)(tid + 256 * m) * N_);

    const size_t TILES = (size_t)BN_ * K_ * T_;

#pragma unroll
    for (int P = 0; P < 2; ++P) {
        const int bn0 = bnb + 2 * P;

        // ---- Bit-reversed pack of pair P into re/im.
        // (Safe vs pair P-1: its last re/im readers -- topk -- were fenced
        //  by the post-topk barrier of iteration P-1.)
#pragma unroll
        for (int m = 0; m < 8; ++m) {
            const int t = tid + 256 * m;
            const int p = sw((int)(__brev((unsigned)t) >> 21));   // rev11(t)
            re[p] = P ? sv[m].z : sv[m].x;
            im[p] = P ? sv[m].w : sv[m].y;
        }
        bar_lgkm();

        // ---- Round 1: radix-8 (stages 1-3), h=1, constant twiddles.
        {
            const int base = tid * 8;
            cf E[8];
#pragma unroll
            for (int j = 0; j < 8; ++j) { const int p = sw(base + j); E[j].r = re[p]; E[j].i = im[p]; }
            bf_1(E[0], E[1]); bf_1(E[2], E[3]); bf_1(E[4], E[5]); bf_1(E[6], E[7]);
            bf_1(E[0], E[2]); bf_mi(E[1], E[3]); bf_1(E[4], E[6]); bf_mi(E[5], E[7]);
            bf_1(E[0], E[4]); bf_w(E[1], E[5], S2_F, -S2_F);
            bf_mi(E[2], E[6]); bf_w(E[3], E[7], -S2_F, -S2_F);
#pragma unroll
            for (int j = 0; j < 8; ++j) { const int p = sw(base + j); re[p] = E[j].r; im[p] = E[j].i; }
        }
        bar_lgkm();

        // ---- Rounds 2,3: radix-8 at stages s=4 (h=8) and s=7 (h=64).
#pragma unroll
        for (int r = 0; r < 2; ++r) {
            const int s    = 4 + 3 * r;
            const int h    = 1 << (s - 1);
            const int bq   = tid & (h - 1);
            const int g    = tid >> (s - 1);
            const int base = g * 8 * h + bq;
            const float2 w1  = tw[bq << (11 - s)];
            const float2 w2a = tw[bq << (10 - s)];
            const float2 w2b = tw[(bq + h) << (10 - s)];
            const float2 w30 = tw[bq << (9 - s)];
            const float2 w31 = tw[(bq + h) << (9 - s)];
            const float2 w32 = tw[(bq + 2 * h) << (9 - s)];
            const float2 w33 = tw[(bq + 3 * h) << (9 - s)];
            cf E[8];
#pragma unroll
            for (int j = 0; j < 8; ++j) { const int p = sw(base + j * h); E[j].r = re[p]; E[j].i = im[p]; }
            bf_w(E[0], E[1], w1.x, w1.y);   bf_w(E[2], E[3], w1.x, w1.y);
            bf_w(E[4], E[5], w1.x, w1.y);   bf_w(E[6], E[7], w1.x, w1.y);
            bf_w(E[0], E[2], w2a.x, w2a.y); bf_w(E[1], E[3], w2b.x, w2b.y);
            bf_w(E[4], E[6], w2a.x, w2a.y); bf_w(E[5], E[7], w2b.x, w2b.y);
            bf_w(E[0], E[4], w30.x, w30.y); bf_w(E[1], E[5], w31.x, w31.y);
            bf_w(E[2], E[6], w32.x, w32.y); bf_w(E[3], E[7], w33.x, w33.y);
#pragma unroll
            for (int j = 0; j < 8; ++j) { const int p = sw(base + j * h); re[p] = E[j].r; im[p] = E[j].i; }
            bar_lgkm();
        }

        // ---- Round 4: radix-4 (stages 10-11), h=512, 2 butterflies/thread.
#pragma unroll
        for (int u = 0; u < 2; ++u) {
            const int bb = tid + 256 * u;
            const float2 wA = tw[bb << 1];
            const float2 wB = tw[bb];
            const float2 wC = tw[bb + 512];
            const int p0 = sw(bb), p1 = sw(bb + 512), p2 = sw(bb + 1024), p3 = sw(bb + 1536);
            cf E0 = {re[p0], im[p0]}, E1 = {re[p1], im[p1]};
            cf E2 = {re[p2], im[p2]}, E3 = {re[p3], im[p3]};
            bf_w(E0, E1, wA.x, wA.y); bf_w(E2, E3, wA.x, wA.y);
            bf_w(E0, E2, wB.x, wB.y); bf_w(E1, E3, wC.x, wC.y);
            re[p0] = E0.r; im[p0] = E0.i; re[p1] = E1.r; im[p1] = E1.i;
            re[p2] = E2.r; im[p2] = E2.i; re[p3] = E3.r; im[p3] = E3.i;
        }
        bar_lgkm();

        // ---- Unpack both spectra; 4*mag^2 (staged via regs, as R4).
        float magsA[4], magsB[4];
#pragma unroll
        for (int m = 0; m < 4; ++m) {
            const int k  = 1 + tid + 256 * m;          // 1..1024
            const int nk = 2048 - k;
            const int pk = sw(k), pn = sw(nk);
            const float zr = re[pk], zi = im[pk];
            const float yr = re[pn], yi = im[pn];
            const float ar = zr + yr, ai = zi - yi;
            const float br = zi + yi, bi = yr - zr;
            magsA[m] = ar * ar + ai * ai;
            magsB[m] = br * br + bi * bi;
        }
        bar_lgkm();
#pragma unroll
        for (int m = 0; m < 4; ++m) {
            const int pk = sw(1 + tid + 256 * m);
            re[pk] = magsA[m];
            im[pk] = magsB[m];
        }
        bar_lgkm();

        // ---- Top-5, intra-wave + register-resident: wave0 -> A, wave1 -> B.
        const int wid  = tid >> 6;
        const int lane = tid & 63;
        if (wid < 2) {
            const float* marr = wid ? im : re;
            float mv[16];
#pragma unroll
            for (int j = 0; j < 16; ++j) mv[j] = marr[sw(1 + lane + 64 * j)];
            for (int it = 0; it < K_; ++it) {
                float bestv = -2.0f;
                int   besti = 1 << 30;
#pragma unroll
                for (int j = 0; j < 16; ++j) {
                    const int k = 1 + lane + 64 * j;
                    if (mv[j] > bestv || (mv[j] == bestv && k < besti)) { bestv = mv[j]; besti = k; }
                }
#pragma unroll
                for (int off = 32; off > 0; off >>= 1) {
                    const float v3 = __shfl_down(bestv, off);
                    const int   i3 = __shfl_down(besti, off);
                    if (v3 > bestv || (v3 == bestv && i3 < besti)) { bestv = v3; besti = i3; }
                }
                const int win = __shfl(besti, 0);      // broadcast winner index
#pragma unroll
                for (int j = 0; j < 16; ++j)
                    if (1 + lane + 64 * j == win) mv[j] = -1.0f;   // exclude
                if (lane == 0) {
                    int period = T_ / win;
                    if (period > PMAX_) period = PMAX_;
                    if (period < MINP_) period = MINP_;
                    const int cyc = T_ / period;
                    sh_take[wid][it] = (period << 16) | (period * cyc); // period|take
                }
            }
        }
        bar_lgkm();   // topk LDS reads + sh_take writes fenced

        // ---- Restore pair-P sequences into sqA/sqB from registers.
        // (Safe vs pair P-1's store-phase ds_reads: each wave drained its
        //  own lgkm at the first barrier of this iteration.)
#pragma unroll
        for (int m = 0; m < 8; ++m) {
            const int t = tid + 256 * m;
            sqA[t] = P ? sv[m].z : sv[m].x;
            sqB[t] = P ? sv[m].w : sv[m].y;
        }
        bar_lgkm();

        // ---- periods / cycles (ints as float32); fire-and-forget.
        if (tid < 2 * K_) {
            const int s2 = tid / K_, k2 = tid % K_;
            const int pk   = sh_take[s2][k2];
            const int per  = pk >> 16;
            const int take = pk & 0xFFFF;
            out[TILES + (size_t)(bn0 + s2) * K_ + k2]                      = (float)per;
            out[TILES + (size_t)BN_ * K_ + (size_t)(bn0 + s2) * K_ + k2]   = (float)(take / per);
        }

        // ---- Tile rows: aligned f4 LDS reads + register shift, regular
        // aligned float4 stores. Fire-and-forget: they drain across pair
        // P+1's load/FFT (no vmcnt barrier until endpgm).
        float* rowA = out + (size_t)bn0 * (K_ * T_);
#pragma unroll
        for (int m = 0; m < 20; ++m) {
            const int e  = tid + 256 * m;
            const int s2 = (e >= K_ * (T_ / 4)) ? 1 : 0;
            const int w  = e - s2 * (K_ * (T_ / 4));
            const int k  = w >> 9;                     // / 512
            const int p4 = (w & 511) << 2;
            const int take  = sh_take[s2][k] & 0xFFFF;
            const int start = T_ - take;
            const vf4* sq4 = (const vf4*)(s2 ? sqB : sqA);
            const int idx = start + p4;
            int a0 = idx >> 2;
            if (a0 > 511) a0 = 511;                    // clamp (masked anyway)
            const int sh = idx & 3;
            const vf4 lo = sq4[a0];
            const vf4 hi = sq4[a0 + 1];
            float r0, r1, r2, r3;
            if (sh == 0)      { r0 = lo.x; r1 = lo.y; r2 = lo.z; r3 = lo.w; }
            else if (sh == 1) { r0 = lo.y; r1 = lo.z; r2 = lo.w; r3 = hi.x; }
            else if (sh == 2) { r0 = lo.z; r1 = lo.w; r2 = hi.x; r3 = hi.y; }
            else              { r0 = lo.w; r1 = hi.x; r2 = hi.y; r3 = hi.z; }
            vf4 vv;
            vv.x = (p4 + 0 < take) ? r0 : 0.0f;
            vv.y = (p4 + 1 < take) ? r1 : 0.0f;
            vv.z = (p4 + 2 < take) ? r2 : 0.0f;
            vv.w = (p4 + 3 < take) ? r3 : 0.0f;
            *(vf4*)(rowA + (size_t)(s2 * K_ + k) * T_ + p4) = vv;
        }
        // No trailing barrier needed: next iteration's first LDS writes
        // (re/im bitrev) touch different arrays than this store phase's
        // reads (sqA/sqB), and each wave's own lgkm drains at the next bar.
    }
}

// ---------------------------------------------------------------------------
extern "C" void kernel_launch(void* const* d_in, const int* in_sizes, int n_in,
                              void* d_out, int out_size, void* d_ws, size_t ws_size,
                              hipStream_t stream) {
    const float* x = (const float*)d_in[0];
    float* out = (float*)d_out;
    float2* tw = (float2*)d_ws;   // 8 KB twiddle table

    pt_twiddle<<<dim3(4), dim3(256), 0, stream>>>(tw);
    pt_fft_tiles<<<dim3(BN_ / 4), dim3(256), 0, stream>>>(x, out, tw);
}

// Round 10
// 215.994 us; speedup vs baseline: 1.1216x; 1.1216x over previous
//
#include <hip/hip_runtime.h>

#define B_ 32
#define T_ 2048
#define N_ 128
#define K_ 5
#define BN_ (B_ * N_)
#define PMAX_ 512
#define MINP_ 2

static constexpr double PI_D = 3.14159265358979323846264338327950288;
static constexpr float  S2_F = 0.70710678118654752440f;  // sqrt(1/2)

typedef float vf4 __attribute__((ext_vector_type(4)));

struct cf { float r, i; };

__device__ __forceinline__ void bf_w(cf& u, cf& v, float wr, float wi) {
    const float tr = v.r * wr - v.i * wi;
    const float ti = v.r * wi + v.i * wr;
    v.r = u.r - tr; v.i = u.i - ti;
    u.r += tr;      u.i += ti;
}
__device__ __forceinline__ void bf_1(cf& u, cf& v) {        // w = 1
    const float tr = v.r, ti = v.i;
    v.r = u.r - tr; v.i = u.i - ti;
    u.r += tr;      u.i += ti;
}
__device__ __forceinline__ void bf_mi(cf& u, cf& v) {       // w = -i
    const float tr = v.i, ti = -v.r;
    v.r = u.r - tr; v.i = u.i - ti;
    u.r += tr;      u.i += ti;
}
// LDS bank swizzle: keeps every hot access pattern low-way on 32 banks.
__device__ __forceinline__ int sw(int i) { return i ^ ((i >> 5) & 31); }

// ---------------------------------------------------------------------------
// Kernel 0: twiddle table tw[m] = exp(-2*pi*i*m/2048) as float2, into d_ws.
// ---------------------------------------------------------------------------
__global__ __launch_bounds__(256) void pt_twiddle(float2* __restrict__ tw) {
    const int m = blockIdx.x * 256 + threadIdx.x;
    if (m < 1024) {
        double s, c;
        sincos(-2.0 * PI_D * (double)m / 2048.0, &s, &c);
        tw[m] = make_float2((float)c, (float)s);
    }
}

// ---------------------------------------------------------------------------
// Final kernel = R4 (session best, 217.3 us total / ~104 us kernel):
//  - Pair rFFT trick: two series per block as one complex 2048-pt FFT
//    (radix-8 x3 + radix-4), sw() bank swizzle, separate re/im arrays.
//  - The 8 float2 x-values are carried in REGISTERS (16 VGPR) across the
//    FFT/top-5; after top-5 the mags are dead and the registers are written
//    linearly into re/im for the store phase. No reload, no seq LDS.
//    16.5 KB LDS -> 7 blocks/CU with __launch_bounds__(256, 7).
//  - float2 column loads preserve inter-block L2 line sharing (FETCH_SIZE
//    16.6 MB < 33.5 MB input: adjacent blocks hit each other's lines).
//  - Top-5 is register-resident + intra-wave (wave0=A, wave1=B, 16 bins/
//    lane, butterfly shuffle + broadcast exclusion): zero barriers.
//  - Tile rows: aligned f4 LDS reads + register shift, REGULAR cached
//    float4 stores (NT measured 5 us slower); stores sit post-last-barrier
//    and drain across endpgm into the next dispatch.
// Measured regressions this session (kept OUT): kernel split (+8 us),
// NT stores (+5), workspace seq carry (+10), 1-series/block radix-4 (+7),
// interleaved-b64 LDS (+12), lgkm-pipeline + 4-col loads (+23).
// ---------------------------------------------------------------------------
__global__ __launch_bounds__(256, 7) void pt_fft_tiles(const float* __restrict__ x,
                                                       float* __restrict__ out,
                                                       const float2* __restrict__ tw) {
    __shared__ __align__(16) float re[2052];   // FFT re / mags A / seq A (+4 slack)
    __shared__ __align__(16) float im[2052];   // FFT im / mags B / seq B (+4 slack)
    __shared__ int sh_take[2][K_];

    // XCD-aware swizzle: blocks with equal (blockIdx & 7) (likely same XCD)
    // get consecutive q -> adjacent x columns -> L2 line reuse.
    const int i0  = blockIdx.x;
    const int q   = ((i0 & 7) << 8) | (i0 >> 3);
    const int bn0 = q * 2;
    const int b   = bn0 >> 7;          // / N_
    const int n   = bn0 & 127;         // even
    const int tid = threadIdx.x;

    // ---- Load x columns (n, n+1): bit-reversed pack into re/im.
    // v[] stays live in registers until the store phase (no reload, no seq LDS).
    const float* xp = x + (size_t)b * T_ * N_ + n;
    float2 v[8];
#pragma unroll
    for (int m = 0; m < 8; ++m)
        v[m] = *(const float2*)(xp + (size_t)(tid + 256 * m) * N_);
#pragma unroll
    for (int m = 0; m < 8; ++m) {
        const int t = tid + 256 * m;
        const int p = sw((int)(__brev((unsigned)t) >> 21));   // pos = rev11(t)
        re[p] = v[m].x;
        im[p] = v[m].y;
    }
    __syncthreads();

    // ---- Round 1: radix-8 (stages 1-3), h=1, constant twiddles.
    {
        const int base = tid * 8;
        cf E[8];
#pragma unroll
        for (int j = 0; j < 8; ++j) { const int p = sw(base + j); E[j].r = re[p]; E[j].i = im[p]; }
        bf_1(E[0], E[1]); bf_1(E[2], E[3]); bf_1(E[4], E[5]); bf_1(E[6], E[7]);
        bf_1(E[0], E[2]); bf_mi(E[1], E[3]); bf_1(E[4], E[6]); bf_mi(E[5], E[7]);
        bf_1(E[0], E[4]); bf_w(E[1], E[5], S2_F, -S2_F);
        bf_mi(E[2], E[6]); bf_w(E[3], E[7], -S2_F, -S2_F);
#pragma unroll
        for (int j = 0; j < 8; ++j) { const int p = sw(base + j); re[p] = E[j].r; im[p] = E[j].i; }
    }
    __syncthreads();

    // ---- Rounds 2,3: radix-8 at stages s=4 (h=8) and s=7 (h=64).
#pragma unroll
    for (int r = 0; r < 2; ++r) {
        const int s    = 4 + 3 * r;
        const int h    = 1 << (s - 1);
        const int bq   = tid & (h - 1);
        const int g    = tid >> (s - 1);
        const int base = g * 8 * h + bq;
        const float2 w1  = tw[bq << (11 - s)];
        const float2 w2a = tw[bq << (10 - s)];
        const float2 w2b = tw[(bq + h) << (10 - s)];
        const float2 w30 = tw[bq << (9 - s)];
        const float2 w31 = tw[(bq + h) << (9 - s)];
        const float2 w32 = tw[(bq + 2 * h) << (9 - s)];
        const float2 w33 = tw[(bq + 3 * h) << (9 - s)];
        cf E[8];
#pragma unroll
        for (int j = 0; j < 8; ++j) { const int p = sw(base + j * h); E[j].r = re[p]; E[j].i = im[p]; }
        bf_w(E[0], E[1], w1.x, w1.y);   bf_w(E[2], E[3], w1.x, w1.y);
        bf_w(E[4], E[5], w1.x, w1.y);   bf_w(E[6], E[7], w1.x, w1.y);
        bf_w(E[0], E[2], w2a.x, w2a.y); bf_w(E[1], E[3], w2b.x, w2b.y);
        bf_w(E[4], E[6], w2a.x, w2a.y); bf_w(E[5], E[7], w2b.x, w2b.y);
        bf_w(E[0], E[4], w30.x, w30.y); bf_w(E[1], E[5], w31.x, w31.y);
        bf_w(E[2], E[6], w32.x, w32.y); bf_w(E[3], E[7], w33.x, w33.y);
#pragma unroll
        for (int j = 0; j < 8; ++j) { const int p = sw(base + j * h); re[p] = E[j].r; im[p] = E[j].i; }
        __syncthreads();
    }

    // ---- Round 4: radix-4 (stages 10-11), h=512, 2 butterflies/thread.
#pragma unroll
    for (int u = 0; u < 2; ++u) {
        const int bb = tid + 256 * u;
        const float2 wA = tw[bb << 1];
        const float2 wB = tw[bb];
        const float2 wC = tw[bb + 512];
        const int p0 = sw(bb), p1 = sw(bb + 512), p2 = sw(bb + 1024), p3 = sw(bb + 1536);
        cf E0 = {re[p0], im[p0]}, E1 = {re[p1], im[p1]};
        cf E2 = {re[p2], im[p2]}, E3 = {re[p3], im[p3]};
        bf_w(E0, E1, wA.x, wA.y); bf_w(E2, E3, wA.x, wA.y);
        bf_w(E0, E2, wB.x, wB.y); bf_w(E1, E3, wC.x, wC.y);
        re[p0] = E0.r; im[p0] = E0.i; re[p1] = E1.r; im[p1] = E1.i;
        re[p2] = E2.r; im[p2] = E2.i; re[p3] = E3.r; im[p3] = E3.i;
    }
    __syncthreads();

    // ---- Unpack both spectra; 4*mag^2 (exact power-of-2 scale, rank-safe).
    float magsA[4], magsB[4];
#pragma unroll
    for (int m = 0; m < 4; ++m) {
        const int k  = 1 + tid + 256 * m;          // 1..1024
        const int nk = 2048 - k;
        const int pk = sw(k), pn = sw(nk);
        const float zr = re[pk], zi = im[pk];
        const float yr = re[pn], yi = im[pn];
        const float ar = zr + yr, ai = zi - yi;
        const float br = zi + yi, bi = yr - zr;
        magsA[m] = ar * ar + ai * ai;
        magsB[m] = br * br + bi * bi;
    }
    __syncthreads();
#pragma unroll
    for (int m = 0; m < 4; ++m) {
        const int pk = sw(1 + tid + 256 * m);
        re[pk] = magsA[m];
        im[pk] = magsB[m];
    }
    __syncthreads();

    // ---- Top-5, intra-wave + register-resident: wave0 -> A (re), wave1 -> B (im).
    // 16 bins/lane; 5 rounds of {local argmax, 6-level butterfly, broadcast,
    // register exclusion}. No barriers, no LDS traffic inside the loop.
    const int wid  = tid >> 6;
    const int lane = tid & 63;
    if (wid < 2) {
        const float* marr = wid ? im : re;
        float mv[16];
#pragma unroll
        for (int j = 0; j < 16; ++j) mv[j] = marr[sw(1 + lane + 64 * j)];
        for (int it = 0; it < K_; ++it) {
            float bestv = -2.0f;
            int   besti = 1 << 30;
#pragma unroll
            for (int j = 0; j < 16; ++j) {
                const int k = 1 + lane + 64 * j;
                if (mv[j] > bestv || (mv[j] == bestv && k < besti)) { bestv = mv[j]; besti = k; }
            }
#pragma unroll
            for (int off = 32; off > 0; off >>= 1) {
                const float v3 = __shfl_down(bestv, off);
                const int   i3 = __shfl_down(besti, off);
                if (v3 > bestv || (v3 == bestv && i3 < besti)) { bestv = v3; besti = i3; }
            }
            const int win = __shfl(besti, 0);      // broadcast winner index
#pragma unroll
            for (int j = 0; j < 16; ++j)
                if (1 + lane + 64 * j == win) mv[j] = -1.0f;   // exclude
            if (lane == 0) {
                int period = T_ / win;
                if (period > PMAX_) period = PMAX_;
                if (period < MINP_) period = MINP_;
                const int cyc = T_ / period;
                sh_take[wid][it] = (period << 16) | (period * cyc); // pack period|take
            }
        }
    }
    __syncthreads();

    // ---- periods / cycles (ints as float32).
    const size_t TILES = (size_t)BN_ * K_ * T_;
    if (tid < 2 * K_) {
        const int s2 = tid / K_, k2 = tid % K_;
        const int pk   = sh_take[s2][k2];
        const int per  = pk >> 16;
        const int take = pk & 0xFFFF;
        out[TILES + (size_t)(bn0 + s2) * K_ + k2]                      = (float)per;
        out[TILES + (size_t)BN_ * K_ + (size_t)(bn0 + s2) * K_ + k2]   = (float)(take / per);
    }

    // ---- Restore sequences linearly into re (A) / im (B) FROM REGISTERS;
    // mags are dead after top-5. No global reload.
#pragma unroll
    for (int m = 0; m < 8; ++m) {
        const int t = tid + 256 * m;
        re[t] = v[m].x;
        im[t] = v[m].y;
    }
    __syncthreads();

    // ---- Tile rows: aligned f4 LDS reads + register shift, REGULAR aligned
    // float4 stores (same shape as the 6.5 TB/s fill kernel).
    float* rowA = out + (size_t)bn0 * (K_ * T_);
#pragma unroll
    for (int m = 0; m < 20; ++m) {
        const int e  = tid + 256 * m;
        const int s2 = (e >= K_ * (T_ / 4)) ? 1 : 0;
        const int w  = e - s2 * (K_ * (T_ / 4));
        const int k  = w >> 9;                     // / 512
        const int p4 = (w & 511) << 2;
        const int take  = sh_take[s2][k] & 0xFFFF;
        const int start = T_ - take;
        const vf4* sq4 = (const vf4*)(s2 ? im : re);
        const int idx = start + p4;
        int a0 = idx >> 2;
        if (a0 > 511) a0 = 511;                    // clamp (masked anyway)
        const int sh = idx & 3;
        const vf4 lo = sq4[a0];
        const vf4 hi = sq4[a0 + 1];
        float r0, r1, r2, r3;
        if (sh == 0)      { r0 = lo.x; r1 = lo.y; r2 = lo.z; r3 = lo.w; }
        else if (sh == 1) { r0 = lo.y; r1 = lo.z; r2 = lo.w; r3 = hi.x; }
        else if (sh == 2) { r0 = lo.z; r1 = lo.w; r2 = hi.x; r3 = hi.y; }
        else              { r0 = lo.w; r1 = hi.x; r2 = hi.y; r3 = hi.z; }
        vf4 vv;
        vv.x = (p4 + 0 < take) ? r0 : 0.0f;
        vv.y = (p4 + 1 < take) ? r1 : 0.0f;
        vv.z = (p4 + 2 < take) ? r2 : 0.0f;
        vv.w = (p4 + 3 < take) ? r3 : 0.0f;
        *(vf4*)(rowA + (size_t)(s2 * K_ + k) * T_ + p4) = vv;
    }
}

// ---------------------------------------------------------------------------
extern "C" void kernel_launch(void* const* d_in, const int* in_sizes, int n_in,
                              void* d_out, int out_size, void* d_ws, size_t ws_size,
                              hipStream_t stream) {
    const float* x = (const float*)d_in[0];
    float* out = (float*)d_out;
    float2* tw = (float2*)d_ws;   // 8 KB twiddle table

    pt_twiddle<<<dim3(4), dim3(256), 0, stream>>>(tw);
    pt_fft_tiles<<<dim3(BN_ / 2), dim3(256), 0, stream>>>(x, out, tw);
}

// Round 11
// 214.846 us; speedup vs baseline: 1.1276x; 1.0053x over previous
//
#include <hip/hip_runtime.h>

#define B_ 32
#define T_ 2048
#define N_ 128
#define K_ 5
#define BN_ (B_ * N_)
#define PMAX_ 512
#define MINP_ 2

static constexpr double PI_D = 3.14159265358979323846264338327950288;
static constexpr float  S2_F = 0.70710678118654752440f;  // sqrt(1/2)

typedef float vf4 __attribute__((ext_vector_type(4)));

struct cf { float r, i; };

__device__ __forceinline__ void bf_w(cf& u, cf& v, float wr, float wi) {
    const float tr = v.r * wr - v.i * wi;
    const float ti = v.r * wi + v.i * wr;
    v.r = u.r - tr; v.i = u.i - ti;
    u.r += tr;      u.i += ti;
}
__device__ __forceinline__ void bf_1(cf& u, cf& v) {        // w = 1
    const float tr = v.r, ti = v.i;
    v.r = u.r - tr; v.i = u.i - ti;
    u.r += tr;      u.i += ti;
}
__device__ __forceinline__ void bf_mi(cf& u, cf& v) {       // w = -i
    const float tr = v.i, ti = -v.r;
    v.r = u.r - tr; v.i = u.i - ti;
    u.r += tr;      u.i += ti;
}
// LDS bank swizzle: keeps every hot access pattern low-way on 32 banks.
__device__ __forceinline__ int sw(int i) { return i ^ ((i >> 5) & 31); }

// Swap lane-bit L with one reg-bit across a register pair (a=low, b=high).
// Moves value at (laneBitL, regBit) to (regBit, laneBitL). Pure data
// movement: bitwise-identical values, no LDS, no barrier.
__device__ __forceinline__ void xsw1(float& a, float& b, int tid, int L) {
    const float snd = (tid & L) ? a : b;
    const float got = __shfl_xor(snd, L, 64);
    if (tid & L) a = got; else b = got;
}
// One full stage: swap lane-bit L with reg-bit R over cf E[8] (re & im).
#define XSTAGE(L, P0a, P0b, P1a, P1b, P2a, P2b, P3a, P3b)                      \
    xsw1(E[P0a].r, E[P0b].r, tid, (L)); xsw1(E[P0a].i, E[P0b].i, tid, (L));    \
    xsw1(E[P1a].r, E[P1b].r, tid, (L)); xsw1(E[P1a].i, E[P1b].i, tid, (L));    \
    xsw1(E[P2a].r, E[P2b].r, tid, (L)); xsw1(E[P2a].i, E[P2b].i, tid, (L));    \
    xsw1(E[P3a].r, E[P3b].r, tid, (L)); xsw1(E[P3a].i, E[P3b].i, tid, (L));

// ---------------------------------------------------------------------------
// Kernel 0: twiddle table tw[m] = exp(-2*pi*i*m/2048) as float2, into d_ws.
// ---------------------------------------------------------------------------
__global__ __launch_bounds__(256) void pt_twiddle(float2* __restrict__ tw) {
    const int m = blockIdx.x * 256 + threadIdx.x;
    if (m < 1024) {
        double s, c;
        sincos(-2.0 * PI_D * (double)m / 2048.0, &s, &c);
        tw[m] = make_float2((float)c, (float)s);
    }
}

// ---------------------------------------------------------------------------
// v11 = R4 with FFT rounds 1-3 fused IN REGISTERS:
//  - Round 1 reads its 8 operands from LDS once; rounds 1->2 and 2->3
//    exchanges are intra-wave lane<->reg-bit transposes via __shfl_xor
//    (exchange 1: lane bits[2:0] <-> reg bits[2:0]; exchange 2: lane
//    bits[5:3] <-> reg bits[2:0]); round 3 writes back to the exact sw()
//    positions R4 produced. Removes 2 of 9 barriers and 64 LDS ops/thread.
//  - Every other phase (load, pack, round 4, mags, top-5, restore, store)
//    is byte-identical to R4 (session best). Values bitwise identical.
// ---------------------------------------------------------------------------
__global__ __launch_bounds__(256, 7) void pt_fft_tiles(const float* __restrict__ x,
                                                       float* __restrict__ out,
                                                       const float2* __restrict__ tw) {
    __shared__ __align__(16) float re[2052];   // FFT re / mags A / seq A (+4 slack)
    __shared__ __align__(16) float im[2052];   // FFT im / mags B / seq B (+4 slack)
    __shared__ int sh_take[2][K_];

    // XCD-aware swizzle: blocks with equal (blockIdx & 7) (likely same XCD)
    // get consecutive q -> adjacent x columns -> L2 line reuse.
    const int i0  = blockIdx.x;
    const int q   = ((i0 & 7) << 8) | (i0 >> 3);
    const int bn0 = q * 2;
    const int b   = bn0 >> 7;          // / N_
    const int n   = bn0 & 127;         // even
    const int tid = threadIdx.x;

    // ---- Load x columns (n, n+1): bit-reversed pack into re/im.
    // v[] stays live in registers until the store phase (no reload, no seq LDS).
    const float* xp = x + (size_t)b * T_ * N_ + n;
    float2 v[8];
#pragma unroll
    for (int m = 0; m < 8; ++m)
        v[m] = *(const float2*)(xp + (size_t)(tid + 256 * m) * N_);
#pragma unroll
    for (int m = 0; m < 8; ++m) {
        const int t = tid + 256 * m;
        const int p = sw((int)(__brev((unsigned)t) >> 21));   // pos = rev11(t)
        re[p] = v[m].x;
        im[p] = v[m].y;
    }
    __syncthreads();

    // ================= FFT rounds 1-3, register-resident =================
    cf E[8];

    // ---- Round 1: radix-8 (stages 1-3), h=1, constant twiddles.
    // E[j] = element tid*8 + j (single LDS read of the packed data).
    {
        const int base = tid * 8;
#pragma unroll
        for (int j = 0; j < 8; ++j) { const int p = sw(base + j); E[j].r = re[p]; E[j].i = im[p]; }
        bf_1(E[0], E[1]); bf_1(E[2], E[3]); bf_1(E[4], E[5]); bf_1(E[6], E[7]);
        bf_1(E[0], E[2]); bf_mi(E[1], E[3]); bf_1(E[4], E[6]); bf_mi(E[5], E[7]);
        bf_1(E[0], E[4]); bf_w(E[1], E[5], S2_F, -S2_F);
        bf_mi(E[2], E[6]); bf_w(E[3], E[7], -S2_F, -S2_F);
    }

    // ---- Exchange 1 (intra-wave, 8-lane groups): lane[2:0] <-> reg[2:0].
    // After: E[j] = X1[(tid>>3)*64 + 8j + (tid&7)] = round 2's operands.
    XSTAGE(1, 0,1, 2,3, 4,5, 6,7)      // lane bit0 <-> reg bit0
    XSTAGE(2, 0,2, 1,3, 4,6, 5,7)      // lane bit1 <-> reg bit1
    XSTAGE(4, 0,4, 1,5, 2,6, 3,7)      // lane bit2 <-> reg bit2

    // ---- Round 2: radix-8 at stage s=4 (h=8), twiddles as R4.
    {
        const int bq = tid & 7;
        const float2 w1  = tw[bq << 7];
        const float2 w2a = tw[bq << 6];
        const float2 w2b = tw[(bq + 8) << 6];
        const float2 w30 = tw[bq << 5];
        const float2 w31 = tw[(bq + 8) << 5];
        const float2 w32 = tw[(bq + 16) << 5];
        const float2 w33 = tw[(bq + 24) << 5];
        bf_w(E[0], E[1], w1.x, w1.y);   bf_w(E[2], E[3], w1.x, w1.y);
        bf_w(E[4], E[5], w1.x, w1.y);   bf_w(E[6], E[7], w1.x, w1.y);
        bf_w(E[0], E[2], w2a.x, w2a.y); bf_w(E[1], E[3], w2b.x, w2b.y);
        bf_w(E[4], E[6], w2a.x, w2a.y); bf_w(E[5], E[7], w2b.x, w2b.y);
        bf_w(E[0], E[4], w30.x, w30.y); bf_w(E[1], E[5], w31.x, w31.y);
        bf_w(E[2], E[6], w32.x, w32.y); bf_w(E[3], E[7], w33.x, w33.y);
    }

    // ---- Exchange 2 (intra-wave, 64-lane): lane[5:3] <-> reg[2:0].
    // After: E[j] = X2[(tid>>6)*512 + 64j + (tid&63)] = round 3's operands.
    XSTAGE(8,  0,1, 2,3, 4,5, 6,7)     // lane bit3 <-> reg bit0
    XSTAGE(16, 0,2, 1,3, 4,6, 5,7)     // lane bit4 <-> reg bit1
    XSTAGE(32, 0,4, 1,5, 2,6, 3,7)     // lane bit5 <-> reg bit2

    // ---- Round 3: radix-8 at stage s=7 (h=64), twiddles as R4; write back
    // to the exact sw() positions R4's round 3 produced.
    {
        const int bq = tid & 63;
        const float2 w1  = tw[bq << 4];
        const float2 w2a = tw[bq << 3];
        const float2 w2b = tw[(bq + 64) << 3];
        const float2 w30 = tw[bq << 2];
        const float2 w31 = tw[(bq + 64) << 2];
        const float2 w32 = tw[(bq + 128) << 2];
        const float2 w33 = tw[(bq + 192) << 2];
        bf_w(E[0], E[1], w1.x, w1.y);   bf_w(E[2], E[3], w1.x, w1.y);
        bf_w(E[4], E[5], w1.x, w1.y);   bf_w(E[6], E[7], w1.x, w1.y);
        bf_w(E[0], E[2], w2a.x, w2a.y); bf_w(E[1], E[3], w2b.x, w2b.y);
        bf_w(E[4], E[6], w2a.x, w2a.y); bf_w(E[5], E[7], w2b.x, w2b.y);
        bf_w(E[0], E[4], w30.x, w30.y); bf_w(E[1], E[5], w31.x, w31.y);
        bf_w(E[2], E[6], w32.x, w32.y); bf_w(E[3], E[7], w33.x, w33.y);
        const int base = (tid >> 6) * 512 + (tid & 63);
#pragma unroll
        for (int j = 0; j < 8; ++j) { const int p = sw(base + j * 64); re[p] = E[j].r; im[p] = E[j].i; }
    }
    __syncthreads();
    // ================= end register-resident rounds =================

    // ---- Round 4: radix-4 (stages 10-11), h=512, 2 butterflies/thread.
#pragma unroll
    for (int u = 0; u < 2; ++u) {
        const int bb = tid + 256 * u;
        const float2 wA = tw[bb << 1];
        const float2 wB = tw[bb];
        const float2 wC = tw[bb + 512];
        const int p0 = sw(bb), p1 = sw(bb + 512), p2 = sw(bb + 1024), p3 = sw(bb + 1536);
        cf E0 = {re[p0], im[p0]}, E1 = {re[p1], im[p1]};
        cf E2 = {re[p2], im[p2]}, E3 = {re[p3], im[p3]};
        bf_w(E0, E1, wA.x, wA.y); bf_w(E2, E3, wA.x, wA.y);
        bf_w(E0, E2, wB.x, wB.y); bf_w(E1, E3, wC.x, wC.y);
        re[p0] = E0.r; im[p0] = E0.i; re[p1] = E1.r; im[p1] = E1.i;
        re[p2] = E2.r; im[p2] = E2.i; re[p3] = E3.r; im[p3] = E3.i;
    }
    __syncthreads();

    // ---- Unpack both spectra; 4*mag^2 (exact power-of-2 scale, rank-safe).
    float magsA[4], magsB[4];
#pragma unroll
    for (int m = 0; m < 4; ++m) {
        const int k  = 1 + tid + 256 * m;          // 1..1024
        const int nk = 2048 - k;
        const int pk = sw(k), pn = sw(nk);
        const float zr = re[pk], zi = im[pk];
        const float yr = re[pn], yi = im[pn];
        const float ar = zr + yr, ai = zi - yi;
        const float br = zi + yi, bi = yr - zr;
        magsA[m] = ar * ar + ai * ai;
        magsB[m] = br * br + bi * bi;
    }
    __syncthreads();
#pragma unroll
    for (int m = 0; m < 4; ++m) {
        const int pk = sw(1 + tid + 256 * m);
        re[pk] = magsA[m];
        im[pk] = magsB[m];
    }
    __syncthreads();

    // ---- Top-5, intra-wave + register-resident: wave0 -> A (re), wave1 -> B (im).
    const int wid  = tid >> 6;
    const int lane = tid & 63;
    if (wid < 2) {
        const float* marr = wid ? im : re;
        float mv[16];
#pragma unroll
        for (int j = 0; j < 16; ++j) mv[j] = marr[sw(1 + lane + 64 * j)];
        for (int it = 0; it < K_; ++it) {
            float bestv = -2.0f;
            int   besti = 1 << 30;
#pragma unroll
            for (int j = 0; j < 16; ++j) {
                const int k = 1 + lane + 64 * j;
                if (mv[j] > bestv || (mv[j] == bestv && k < besti)) { bestv = mv[j]; besti = k; }
            }
#pragma unroll
            for (int off = 32; off > 0; off >>= 1) {
                const float v3 = __shfl_down(bestv, off);
                const int   i3 = __shfl_down(besti, off);
                if (v3 > bestv || (v3 == bestv && i3 < besti)) { bestv = v3; besti = i3; }
            }
            const int win = __shfl(besti, 0);      // broadcast winner index
#pragma unroll
            for (int j = 0; j < 16; ++j)
                if (1 + lane + 64 * j == win) mv[j] = -1.0f;   // exclude
            if (lane == 0) {
                int period = T_ / win;
                if (period > PMAX_) period = PMAX_;
                if (period < MINP_) period = MINP_;
                const int cyc = T_ / period;
                sh_take[wid][it] = (period << 16) | (period * cyc); // pack period|take
            }
        }
    }
    __syncthreads();

    // ---- periods / cycles (ints as float32).
    const size_t TILES = (size_t)BN_ * K_ * T_;
    if (tid < 2 * K_) {
        const int s2 = tid / K_, k2 = tid % K_;
        const int pk   = sh_take[s2][k2];
        const int per  = pk >> 16;
        const int take = pk & 0xFFFF;
        out[TILES + (size_t)(bn0 + s2) * K_ + k2]                      = (float)per;
        out[TILES + (size_t)BN_ * K_ + (size_t)(bn0 + s2) * K_ + k2]   = (float)(take / per);
    }

    // ---- Restore sequences linearly into re (A) / im (B) FROM REGISTERS;
    // mags are dead after top-5. No global reload.
#pragma unroll
    for (int m = 0; m < 8; ++m) {
        const int t = tid + 256 * m;
        re[t] = v[m].x;
        im[t] = v[m].y;
    }
    __syncthreads();

    // ---- Tile rows: aligned f4 LDS reads + register shift, REGULAR aligned
    // float4 stores (same shape as the 6.5 TB/s fill kernel).
    float* rowA = out + (size_t)bn0 * (K_ * T_);
#pragma unroll
    for (int m = 0; m < 20; ++m) {
        const int e  = tid + 256 * m;
        const int s2 = (e >= K_ * (T_ / 4)) ? 1 : 0;
        const int w  = e - s2 * (K_ * (T_ / 4));
        const int k  = w >> 9;                     // / 512
        const int p4 = (w & 511) << 2;
        const int take  = sh_take[s2][k] & 0xFFFF;
        const int start = T_ - take;
        const vf4* sq4 = (const vf4*)(s2 ? im : re);
        const int idx = start + p4;
        int a0 = idx >> 2;
        if (a0 > 511) a0 = 511;                    // clamp (masked anyway)
        const int sh = idx & 3;
        const vf4 lo = sq4[a0];
        const vf4 hi = sq4[a0 + 1];
        float r0, r1, r2, r3;
        if (sh == 0)      { r0 = lo.x; r1 = lo.y; r2 = lo.z; r3 = lo.w; }
        else if (sh == 1) { r0 = lo.y; r1 = lo.z; r2 = lo.w; r3 = hi.x; }
        else if (sh == 2) { r0 = lo.z; r1 = lo.w; r2 = hi.x; r3 = hi.y; }
        else              { r0 = lo.w; r1 = hi.x; r2 = hi.y; r3 = hi.z; }
        vf4 vv;
        vv.x = (p4 + 0 < take) ? r0 : 0.0f;
        vv.y = (p4 + 1 < take) ? r1 : 0.0f;
        vv.z = (p4 + 2 < take) ? r2 : 0.0f;
        vv.w = (p4 + 3 < take) ? r3 : 0.0f;
        *(vf4*)(rowA + (size_t)(s2 * K_ + k) * T_ + p4) = vv;
    }
}

// ---------------------------------------------------------------------------
extern "C" void kernel_launch(void* const* d_in, const int* in_sizes, int n_in,
                              void* d_out, int out_size, void* d_ws, size_t ws_size,
                              hipStream_t stream) {
    const float* x = (const float*)d_in[0];
    float* out = (float*)d_out;
    float2* tw = (float2*)d_ws;   // 8 KB twiddle table

    pt_twiddle<<<dim3(4), dim3(256), 0, stream>>>(tw);
    pt_fft_tiles<<<dim3(BN_ / 2), dim3(256), 0, stream>>>(x, out, tw);
}